// Round 2
// baseline (269.556 us; speedup 1.0000x reference)
//
#include <hip/hip_runtime.h>
#include <hip/hip_cooperative_groups.h>
#include <math.h>

namespace cg = cooperative_groups;

#define HDIM 512
#define NROWS 100000
#define GATHER_BLOCKS 64
#define MAXBLK 1024

// ---- workspace layout (float indices) ----
constexpr int SIMS_OFF   = 0;                      // [NROWS] sims (= -||K-cue||^2)
constexpr int BMIN_OFF   = NROWS;                  // [MAXBLK] per-block min of ||K-cue||^2
constexpr int PREACT_OFF = NROWS + MAXBLK;         // [5*HDIM]
constexpr int PM_OFF     = PREACT_OFF + 5 * HDIM;  // [64*HDIM] partial e*V
constexpr int PD_OFF     = PM_OFF + GATHER_BLOCKS * HDIM;  // [64] partial e

__device__ __forceinline__ float wave_sum(float v) {
    #pragma unroll
    for (int off = 32; off; off >>= 1) v += __shfl_xor(v, off);
    return v;
}
__device__ __forceinline__ float wave_min(float v) {
    #pragma unroll
    for (int off = 32; off; off >>= 1) v = fminf(v, __shfl_xor(v, off));
    return v;
}
__device__ __forceinline__ float d2sum(float4 a, float4 c) {
    float d, s;
    d = a.x - c.x; s  = d * d;
    d = a.y - c.y; s += d * d;
    d = a.z - c.z; s += d * d;
    d = a.w - c.w; s += d * d;
    return s;
}

__global__ __launch_bounds__(256, 4)
void k_fused(const float* __restrict__ state, const float* __restrict__ pa,
             const float* __restrict__ pr, const float* __restrict__ ts,
             const float* __restrict__ cue, const float* __restrict__ K,
             const float* __restrict__ V, const float* __restrict__ Wx,
             const float* __restrict__ Wh, const float* __restrict__ b,
             const float* __restrict__ aw, const float* __restrict__ ab,
             const float* __restrict__ cw, const float* __restrict__ cb,
             const float* __restrict__ h0, const float* __restrict__ c0,
             float* __restrict__ ws, float* __restrict__ out) {
    cg::grid_group grid = cg::this_grid();
    const int lane = threadIdx.x & 63;
    const int wib  = threadIdx.x >> 6;
    const int gw   = blockIdx.x * 4 + wib;
    const int nw   = gridDim.x * 4;

    // ================= phase 1a: LSTM pre-activations (hides under sims BW) ==
    {
        float x0 = state[lane];
        float x1 = 0.f;
        if      (lane < 4)  x1 = pa[lane];
        else if (lane == 4) x1 = pr[0];
        else if (lane == 5) x1 = ts[0];

        const float4* h04 = (const float4*)h0;
        const float4  hA = h04[lane], hB = h04[64 + lane];

        for (int row = gw; row < 5 * HDIM; row += nw) {
            const float4* wh4 = (const float4*)(Wh + (size_t)row * HDIM);
            const float4 a0 = wh4[lane], a1 = wh4[64 + lane];
            float acc = a0.x*hA.x + a0.y*hA.y + a0.z*hA.z + a0.w*hA.w
                      + a1.x*hB.x + a1.y*hB.y + a1.z*hB.z + a1.w*hB.w;
            const float* wxr = Wx + (size_t)row * 70;
            acc += wxr[lane] * x0;
            if (lane < 6) acc += wxr[64 + lane] * x1;
            acc = wave_sum(acc);
            if (lane == 0) ws[PREACT_OFF + row] = acc + b[row];
        }
    }

    // ================= phase 1b: sims sweep (dominant, HBM-bound) ============
    {
        const float4* c4 = (const float4*)cue;
        const float4 cA = c4[lane], cB = c4[64 + lane];
        float minss = INFINITY;

        for (int n = gw; n < NROWS; n += 2 * nw) {
            const int n2 = n + nw;
            const bool has2 = (n2 < NROWS);
            const float4* k4a = (const float4*)(K + (size_t)n * HDIM);
            const float4* k4b = (const float4*)(K + (size_t)(has2 ? n2 : n) * HDIM);
            const float4 a0 = k4a[lane], a1 = k4a[64 + lane];
            const float4 b0 = k4b[lane], b1 = k4b[64 + lane];
            float ss1 = d2sum(a0, cA) + d2sum(a1, cB);
            float ss2 = d2sum(b0, cA) + d2sum(b1, cB);
            ss1 = wave_sum(ss1);
            ss2 = wave_sum(ss2);
            if (lane == 0) {
                ws[SIMS_OFF + n] = -ss1;
                if (has2) ws[SIMS_OFF + n2] = -ss2;
            }
            minss = fminf(minss, ss1);
            if (has2) minss = fminf(minss, ss2);
        }

        minss = wave_min(minss);
        __shared__ float smin[4];
        if (lane == 0) smin[wib] = minss;
        __syncthreads();
        if (threadIdx.x == 0)
            ws[BMIN_OFF + blockIdx.x] =
                fminf(fminf(smin[0], smin[1]), fminf(smin[2], smin[3]));
    }

    grid.sync();

    // ================= phase 2: gather surviving V rows (blocks 0..63) =======
    if (blockIdx.x < GATHER_BLOCKS) {
        // every gather block computes the same global max -> deterministic
        float mn = INFINITY;
        for (int i = threadIdx.x; i < (int)gridDim.x; i += 256)
            mn = fminf(mn, ws[BMIN_OFF + i]);
        mn = wave_min(mn);
        __shared__ float sred[4];
        if (lane == 0) sred[wib] = mn;
        __syncthreads();
        const float smax = -fminf(fminf(sred[0], sred[1]), fminf(sred[2], sred[3]));

        const int gwid = blockIdx.x * 4 + wib;   // 256 gather waves
        float4 accA = {0.f,0.f,0.f,0.f}, accB = {0.f,0.f,0.f,0.f};
        float dsum = 0.f;

        const int nchunks = (NROWS + 63) / 64;
        for (int c = gwid; c < nchunks; c += GATHER_BLOCKS * 4) {
            const int n = c * 64 + lane;
            const bool valid = (n < NROWS);
            const float s = valid ? ws[SIMS_OFF + n] : -INFINITY;
            const float e = expf(s - smax);      // underflows to 0 for far rows
            dsum += e;                            // exact denominator
            unsigned long long mask = __ballot(valid && (s - smax >= -30.0f));
            while (mask) {
                const int bpos = __ffsll(mask) - 1;
                mask &= mask - 1;
                const int nb = c * 64 + bpos;
                const float eb = __shfl(e, bpos);
                const float4* v4 = (const float4*)(V + (size_t)nb * HDIM);
                const float4 vA = v4[lane], vB = v4[64 + lane];
                accA.x += eb * vA.x; accA.y += eb * vA.y;
                accA.z += eb * vA.z; accA.w += eb * vA.w;
                accB.x += eb * vB.x; accB.y += eb * vB.y;
                accB.z += eb * vB.z; accB.w += eb * vB.w;
            }
        }
        dsum = wave_sum(dsum);

        __shared__ float lm[4][HDIM];
        __shared__ float ld[4];
        float* rowp = lm[wib];
        rowp[lane*4 + 0]       = accA.x; rowp[lane*4 + 1]       = accA.y;
        rowp[lane*4 + 2]       = accA.z; rowp[lane*4 + 3]       = accA.w;
        rowp[256 + lane*4 + 0] = accB.x; rowp[256 + lane*4 + 1] = accB.y;
        rowp[256 + lane*4 + 2] = accB.z; rowp[256 + lane*4 + 3] = accB.w;
        if (lane == 0) ld[wib] = dsum;
        __syncthreads();

        const int t = threadIdx.x;
        ws[PM_OFF + blockIdx.x * HDIM + t] =
            lm[0][t] + lm[1][t] + lm[2][t] + lm[3][t];
        ws[PM_OFF + blockIdx.x * HDIM + 256 + t] =
            lm[0][256+t] + lm[1][256+t] + lm[2][256+t] + lm[3][256+t];
        if (t == 0)
            ws[PD_OFF + blockIdx.x] = ld[0] + ld[1] + ld[2] + ld[3];
    }

    grid.sync();

    // ================= phase 3: final reduce + cell + heads (block 0) ========
    if (blockIdx.x == 0) {
        const int t = threadIdx.x;       // 256 threads, each owns t and t+256
        __shared__ float hl[HDIM];
        __shared__ float sden;
        __shared__ float logits[4];

        if (wib == 0) {
            float d = ws[PD_OFF + lane];  // 64 partials, one per lane
            d = wave_sum(d);
            if (lane == 0) sden = d;
        }
        float m0 = 0.f, m1 = 0.f;
        #pragma unroll 8
        for (int b2 = 0; b2 < GATHER_BLOCKS; b2++) {
            m0 += ws[PM_OFF + b2 * HDIM + t];
            m1 += ws[PM_OFF + b2 * HDIM + 256 + t];
        }
        __syncthreads();
        const float inv_den = 1.f / sden;
        m0 *= inv_den; m1 *= inv_den;

        #pragma unroll
        for (int half = 0; half < 2; half++) {
            const int tt = t + half * 256;
            const float mm = half ? m1 : m0;
            const float pf = ws[PREACT_OFF + tt];
            const float pi = ws[PREACT_OFF + HDIM + tt];
            const float po = ws[PREACT_OFF + 2*HDIM + tt];
            const float prg= ws[PREACT_OFF + 3*HDIM + tt];
            const float pc = ws[PREACT_OFF + 4*HDIM + tt];
            const float f_t = 1.f / (1.f + expf(-pf));
            const float i_t = 1.f / (1.f + expf(-pi));
            const float o_t = 1.f / (1.f + expf(-po));
            const float r_t = 1.f / (1.f + expf(-prg));
            const float chat = tanhf(pc);
            const float ct = f_t * c0[tt] + i_t * chat + r_t * mm;
            const float ht = o_t * tanhf(ct);
            out[517 + tt] = ct;
            out[5 + tt]   = ht;
            hl[tt] = ht;
        }
        __syncthreads();

        if (wib < 4) {       // actor logits, one wave per row
            float acc = 0.f;
            #pragma unroll
            for (int j = 0; j < HDIM; j += 64)
                acc += aw[wib * HDIM + j + lane] * hl[j + lane];
            acc = wave_sum(acc);
            if (lane == 0) logits[wib] = acc + ab[wib];
        }
        if (wib == 0) {      // critic
            float acc = 0.f;
            #pragma unroll
            for (int j = 0; j < HDIM; j += 64)
                acc += cw[j + lane] * hl[j + lane];
            acc = wave_sum(acc);
            if (lane == 0) out[4] = acc + cb[0];
        }
        __syncthreads();

        if (t == 0) {
            const float mx = fmaxf(fmaxf(logits[0], logits[1]),
                                   fmaxf(logits[2], logits[3]));
            const float e0 = expf(logits[0] - mx), e1 = expf(logits[1] - mx);
            const float e2 = expf(logits[2] - mx), e3 = expf(logits[3] - mx);
            const float inv = 1.f / (e0 + e1 + e2 + e3);
            out[0] = e0 * inv; out[1] = e1 * inv;
            out[2] = e2 * inv; out[3] = e3 * inv;
        }
    }
}

extern "C" void kernel_launch(void* const* d_in, const int* in_sizes, int n_in,
                              void* d_out, int out_size, void* d_ws, size_t ws_size,
                              hipStream_t stream) {
    const float* state  = (const float*)d_in[0];
    const float* pa     = (const float*)d_in[1];
    const float* pr     = (const float*)d_in[2];
    const float* ts     = (const float*)d_in[3];
    const float* cue    = (const float*)d_in[4];
    const float* keys   = (const float*)d_in[5];
    const float* vals   = (const float*)d_in[6];
    const float* Wx     = (const float*)d_in[7];
    const float* Wh     = (const float*)d_in[8];
    const float* b      = (const float*)d_in[9];
    const float* aw     = (const float*)d_in[10];
    const float* ab     = (const float*)d_in[11];
    const float* cw     = (const float*)d_in[12];
    const float* cb     = (const float*)d_in[13];
    const float* h0     = (const float*)d_in[14];
    const float* c0     = (const float*)d_in[15];
    float* ws  = (float*)d_ws;
    float* out = (float*)d_out;

    int dev = 0;
    (void)hipGetDevice(&dev);
    int cus = 256;
    (void)hipDeviceGetAttribute(&cus, hipDeviceAttributeMultiprocessorCount, dev);
    int maxb = 0;
    (void)hipOccupancyMaxActiveBlocksPerMultiprocessor(
        &maxb, (const void*)k_fused, 256, 0);
    if (maxb < 1) maxb = 1;
    long cap = (long)maxb * (long)cus;
    int nblk = (cap < MAXBLK) ? (int)cap : MAXBLK;
    if (nblk < GATHER_BLOCKS) nblk = GATHER_BLOCKS;

    void* args[] = {
        (void*)&state, (void*)&pa, (void*)&pr, (void*)&ts, (void*)&cue,
        (void*)&keys, (void*)&vals, (void*)&Wx, (void*)&Wh, (void*)&b,
        (void*)&aw, (void*)&ab, (void*)&cw, (void*)&cb, (void*)&h0,
        (void*)&c0, (void*)&ws, (void*)&out
    };
    (void)hipLaunchCooperativeKernel((const void*)k_fused, dim3(nblk), dim3(256),
                                     args, 0, stream);
}

// Round 3
// 58.328 us; speedup vs baseline: 4.6214x; 4.6214x over previous
//
#include <hip/hip_runtime.h>
#include <math.h>

#define HDIM 512
#define NROWS 100000
#define NBLK_A 2048
#define NBLK_B 64

// ---- workspace layout (float indices) ----
constexpr int SIMS_OFF   = 0;                        // [NROWS] sims = -||K-cue||^2
constexpr int BMIN_OFF   = NROWS;                    // [NBLK_A] per-block min ||K-cue||^2
constexpr int CNT_OFF    = BMIN_OFF + NBLK_A;        // [1] int ticket counter
constexpr int PREACT_OFF = CNT_OFF + 1;              // [5*HDIM]
constexpr int PM_OFF     = PREACT_OFF + 5 * HDIM;    // [NBLK_B*HDIM] partial e*V
constexpr int PD_OFF     = PM_OFF + NBLK_B * HDIM;   // [NBLK_B] partial e

__device__ __forceinline__ float wave_sum(float v) {
    #pragma unroll
    for (int off = 32; off; off >>= 1) v += __shfl_xor(v, off);
    return v;
}
__device__ __forceinline__ float wave_min(float v) {
    #pragma unroll
    for (int off = 32; off; off >>= 1) v = fminf(v, __shfl_xor(v, off));
    return v;
}
__device__ __forceinline__ float d2sum(float4 a, float4 c) {
    float d, s;
    d = a.x - c.x; s  = d * d;
    d = a.y - c.y; s += d * d;
    d = a.z - c.z; s += d * d;
    d = a.w - c.w; s += d * d;
    return s;
}

// ================= kernel A: preact + sims sweep + per-block min =============
__global__ __launch_bounds__(256)
void kA(const float* __restrict__ state, const float* __restrict__ pa,
        const float* __restrict__ pr, const float* __restrict__ ts,
        const float* __restrict__ cue, const float* __restrict__ K,
        const float* __restrict__ Wx, const float* __restrict__ Wh,
        const float* __restrict__ b, const float* __restrict__ h0,
        float* __restrict__ ws) {
    if (blockIdx.x == 0 && threadIdx.x == 0)
        ((int*)ws)[CNT_OFF] = 0;   // ticket for kernel B (stream-ordered: B starts after A)

    const int lane = threadIdx.x & 63;
    const int wib  = threadIdx.x >> 6;
    const int gw   = blockIdx.x * 4 + wib;
    const int nw   = NBLK_A * 4;                 // 8192 waves

    // ---- preact rows (first 2560 waves; hides under the BW-bound sweep) ----
    if (gw < 5 * HDIM) {
        const int row = gw;
        float x0 = state[lane];
        float x1 = 0.f;
        if      (lane < 4)  x1 = pa[lane];
        else if (lane == 4) x1 = pr[0];
        else if (lane == 5) x1 = ts[0];

        const float4* h04 = (const float4*)h0;
        const float4  hA = h04[lane], hB = h04[64 + lane];
        const float4* wh4 = (const float4*)(Wh + (size_t)row * HDIM);
        const float4 a0 = wh4[lane], a1 = wh4[64 + lane];
        float acc = a0.x*hA.x + a0.y*hA.y + a0.z*hA.z + a0.w*hA.w
                  + a1.x*hB.x + a1.y*hB.y + a1.z*hB.z + a1.w*hB.w;
        const float* wxr = Wx + (size_t)row * 70;
        acc += wxr[lane] * x0;
        if (lane < 6) acc += wxr[64 + lane] * x1;
        acc = wave_sum(acc);
        if (lane == 0) ws[PREACT_OFF + row] = acc + b[row];
    }

    // ---- sims sweep (dominant, HBM/L3-bound) ----
    const float4* c4 = (const float4*)cue;
    const float4 cA = c4[lane], cB = c4[64 + lane];
    float minss = INFINITY;

    for (int n = gw; n < NROWS; n += 2 * nw) {
        const int n2 = n + nw;
        const bool has2 = (n2 < NROWS);
        const float4* k4a = (const float4*)(K + (size_t)n * HDIM);
        const float4* k4b = (const float4*)(K + (size_t)(has2 ? n2 : n) * HDIM);
        const float4 a0 = k4a[lane], a1 = k4a[64 + lane];
        const float4 b0 = k4b[lane], b1 = k4b[64 + lane];
        float ss1 = d2sum(a0, cA) + d2sum(a1, cB);
        float ss2 = d2sum(b0, cA) + d2sum(b1, cB);
        ss1 = wave_sum(ss1);
        ss2 = wave_sum(ss2);
        if (lane == 0) {
            ws[SIMS_OFF + n] = -ss1;
            if (has2) ws[SIMS_OFF + n2] = -ss2;
        }
        minss = fminf(minss, ss1);
        if (has2) minss = fminf(minss, ss2);
    }

    minss = wave_min(minss);
    __shared__ float smin[4];
    if (lane == 0) smin[wib] = minss;
    __syncthreads();
    if (threadIdx.x == 0)
        ws[BMIN_OFF + blockIdx.x] =
            fminf(fminf(smin[0], smin[1]), fminf(smin[2], smin[3]));
}

// ====== kernel B: global max + gather + partials + ticketed final ============
__global__ __launch_bounds__(256)
void kB(const float* __restrict__ V, const float* __restrict__ c0,
        const float* __restrict__ aw, const float* __restrict__ ab,
        const float* __restrict__ cw, const float* __restrict__ cb,
        float* __restrict__ ws, float* __restrict__ out) {
    const int lane = threadIdx.x & 63;
    const int wib  = threadIdx.x >> 6;
    const int t    = threadIdx.x;

    // ---- every block computes the identical global max (deterministic) ----
    float mn = INFINITY;
    #pragma unroll
    for (int i = 0; i < NBLK_A / 256; i++)
        mn = fminf(mn, ws[BMIN_OFF + i * 256 + t]);
    mn = wave_min(mn);
    __shared__ float sred[4];
    if (lane == 0) sred[wib] = mn;
    __syncthreads();
    const float smax = -fminf(fminf(sred[0], sred[1]), fminf(sred[2], sred[3]));

    // ---- gather surviving V rows ----
    const int gwid = blockIdx.x * 4 + wib;        // 256 gather waves
    float4 accA = {0.f,0.f,0.f,0.f}, accB = {0.f,0.f,0.f,0.f};
    float dsum = 0.f;

    const int nchunks = (NROWS + 63) / 64;
    for (int c = gwid; c < nchunks; c += NBLK_B * 4) {
        const int n = c * 64 + lane;
        const bool valid = (n < NROWS);
        const float s = valid ? ws[SIMS_OFF + n] : -INFINITY;
        const float e = expf(s - smax);          // underflows to 0 for far rows
        dsum += e;                                // exact denominator
        unsigned long long mask = __ballot(valid && (s - smax >= -30.0f));
        while (mask) {
            const int bpos = __ffsll(mask) - 1;
            mask &= mask - 1;
            const int nb = c * 64 + bpos;
            const float eb = __shfl(e, bpos);
            const float4* v4 = (const float4*)(V + (size_t)nb * HDIM);
            const float4 vA = v4[lane], vB = v4[64 + lane];
            accA.x += eb * vA.x; accA.y += eb * vA.y;
            accA.z += eb * vA.z; accA.w += eb * vA.w;
            accB.x += eb * vB.x; accB.y += eb * vB.y;
            accB.z += eb * vB.z; accB.w += eb * vB.w;
        }
    }
    dsum = wave_sum(dsum);

    __shared__ float lm[4][HDIM];
    __shared__ float ld[4];
    {
        float* rowp = lm[wib];
        rowp[lane*4 + 0]       = accA.x; rowp[lane*4 + 1]       = accA.y;
        rowp[lane*4 + 2]       = accA.z; rowp[lane*4 + 3]       = accA.w;
        rowp[256 + lane*4 + 0] = accB.x; rowp[256 + lane*4 + 1] = accB.y;
        rowp[256 + lane*4 + 2] = accB.z; rowp[256 + lane*4 + 3] = accB.w;
        if (lane == 0) ld[wib] = dsum;
    }
    __syncthreads();

    ws[PM_OFF + blockIdx.x * HDIM + t] =
        lm[0][t] + lm[1][t] + lm[2][t] + lm[3][t];
    ws[PM_OFF + blockIdx.x * HDIM + 256 + t] =
        lm[0][256+t] + lm[1][256+t] + lm[2][256+t] + lm[3][256+t];
    if (t == 0)
        ws[PD_OFF + blockIdx.x] = ld[0] + ld[1] + ld[2] + ld[3];

    // ---- ticket: last block to finish does the final reduce + cell + heads --
    __threadfence();                              // release partials (device scope)
    __shared__ int sOld;
    if (t == 0) sOld = atomicAdd((int*)ws + CNT_OFF, 1);
    __syncthreads();
    if (sOld != NBLK_B - 1) return;
    __threadfence();                              // acquire others' partials

    __shared__ float hl[HDIM];
    __shared__ float sden;
    __shared__ float logits[4];

    if (wib == 0) {
        float d = ws[PD_OFF + lane];              // 64 partials, one per lane
        d = wave_sum(d);
        if (lane == 0) sden = d;
    }
    float m0 = 0.f, m1 = 0.f;
    #pragma unroll 8
    for (int b2 = 0; b2 < NBLK_B; b2++) {
        m0 += ws[PM_OFF + b2 * HDIM + t];
        m1 += ws[PM_OFF + b2 * HDIM + 256 + t];
    }
    __syncthreads();
    const float inv_den = 1.f / sden;
    m0 *= inv_den; m1 *= inv_den;

    #pragma unroll
    for (int half = 0; half < 2; half++) {
        const int tt = t + half * 256;
        const float mm = half ? m1 : m0;
        const float pf = ws[PREACT_OFF + tt];
        const float pi = ws[PREACT_OFF + HDIM + tt];
        const float po = ws[PREACT_OFF + 2*HDIM + tt];
        const float prg= ws[PREACT_OFF + 3*HDIM + tt];
        const float pc = ws[PREACT_OFF + 4*HDIM + tt];
        const float f_t = 1.f / (1.f + expf(-pf));
        const float i_t = 1.f / (1.f + expf(-pi));
        const float o_t = 1.f / (1.f + expf(-po));
        const float r_t = 1.f / (1.f + expf(-prg));
        const float chat = tanhf(pc);
        const float ct = f_t * c0[tt] + i_t * chat + r_t * mm;
        const float ht = o_t * tanhf(ct);
        out[517 + tt] = ct;
        out[5 + tt]   = ht;
        hl[tt] = ht;
    }
    __syncthreads();

    if (wib < 4) {       // actor logits, one wave per row
        float acc = 0.f;
        #pragma unroll
        for (int j = 0; j < HDIM; j += 64)
            acc += aw[wib * HDIM + j + lane] * hl[j + lane];
        acc = wave_sum(acc);
        if (lane == 0) logits[wib] = acc + ab[wib];
    }
    if (wib == 0) {      // critic
        float acc = 0.f;
        #pragma unroll
        for (int j = 0; j < HDIM; j += 64)
            acc += cw[j + lane] * hl[j + lane];
        acc = wave_sum(acc);
        if (lane == 0) out[4] = acc + cb[0];
    }
    __syncthreads();

    if (t == 0) {
        const float mx = fmaxf(fmaxf(logits[0], logits[1]),
                               fmaxf(logits[2], logits[3]));
        const float e0 = expf(logits[0] - mx), e1 = expf(logits[1] - mx);
        const float e2 = expf(logits[2] - mx), e3 = expf(logits[3] - mx);
        const float inv = 1.f / (e0 + e1 + e2 + e3);
        out[0] = e0 * inv; out[1] = e1 * inv;
        out[2] = e2 * inv; out[3] = e3 * inv;
    }
}

extern "C" void kernel_launch(void* const* d_in, const int* in_sizes, int n_in,
                              void* d_out, int out_size, void* d_ws, size_t ws_size,
                              hipStream_t stream) {
    const float* state  = (const float*)d_in[0];
    const float* pa     = (const float*)d_in[1];
    const float* pr     = (const float*)d_in[2];
    const float* ts     = (const float*)d_in[3];
    const float* cue    = (const float*)d_in[4];
    const float* keys   = (const float*)d_in[5];
    const float* vals   = (const float*)d_in[6];
    const float* Wx     = (const float*)d_in[7];
    const float* Wh     = (const float*)d_in[8];
    const float* b      = (const float*)d_in[9];
    const float* aw     = (const float*)d_in[10];
    const float* ab     = (const float*)d_in[11];
    const float* cw     = (const float*)d_in[12];
    const float* cb     = (const float*)d_in[13];
    const float* h0     = (const float*)d_in[14];
    const float* c0     = (const float*)d_in[15];
    float* ws  = (float*)d_ws;
    float* out = (float*)d_out;

    kA<<<NBLK_A, 256, 0, stream>>>(state, pa, pr, ts, cue, keys, Wx, Wh, b, h0, ws);
    kB<<<NBLK_B, 256, 0, stream>>>(vals, c0, aw, ab, cw, cb, ws, out);
}

// Round 4
// 57.600 us; speedup vs baseline: 4.6798x; 1.0126x over previous
//
#include <hip/hip_runtime.h>
#include <math.h>

#define HDIM 512
#define NROWS 100000
#define NBLK_A 2048
#define NBLK_B 64

// ---- workspace layout (float indices) ----
constexpr int SIMS_OFF   = 0;                        // [NROWS] sims = -||K-cue||^2
constexpr int BMIN_OFF   = NROWS;                    // [NBLK_A] per-block min ||K-cue||^2
constexpr int CNT_OFF    = BMIN_OFF + NBLK_A;        // [1] int ticket counter
constexpr int PREACT_OFF = CNT_OFF + 1;              // [5*HDIM]
constexpr int PM_OFF     = PREACT_OFF + 5 * HDIM;    // [NBLK_B*HDIM] partial e*V
constexpr int PD_OFF     = PM_OFF + NBLK_B * HDIM;   // [NBLK_B] partial e

__device__ __forceinline__ float wave_sum(float v) {
    #pragma unroll
    for (int off = 32; off; off >>= 1) v += __shfl_xor(v, off);
    return v;
}
__device__ __forceinline__ float wave_min(float v) {
    #pragma unroll
    for (int off = 32; off; off >>= 1) v = fminf(v, __shfl_xor(v, off));
    return v;
}
__device__ __forceinline__ float d2sum(float4 a, float4 c) {
    float d, s;
    d = a.x - c.x; s  = d * d;
    d = a.y - c.y; s += d * d;
    d = a.z - c.z; s += d * d;
    d = a.w - c.w; s += d * d;
    return s;
}

// ================= kernel A: preact + sims sweep + per-block min =============
__global__ __launch_bounds__(256)
void kA(const float* __restrict__ state, const float* __restrict__ pa,
        const float* __restrict__ pr, const float* __restrict__ ts,
        const float* __restrict__ cue, const float* __restrict__ K,
        const float* __restrict__ Wx, const float* __restrict__ Wh,
        const float* __restrict__ b, const float* __restrict__ h0,
        float* __restrict__ ws) {
    if (blockIdx.x == 0 && threadIdx.x == 0)
        ((int*)ws)[CNT_OFF] = 0;   // ticket for kernel B (stream-ordered: B after A)

    const int lane = threadIdx.x & 63;
    const int wib  = threadIdx.x >> 6;
    const int gw   = blockIdx.x * 4 + wib;
    const int nw   = NBLK_A * 4;                 // 8192 waves

    // ---- preact rows (first 2560 waves; hides under the BW-bound sweep) ----
    if (gw < 5 * HDIM) {
        const int row = gw;
        float x0 = state[lane];
        float x1 = 0.f;
        if      (lane < 4)  x1 = pa[lane];
        else if (lane == 4) x1 = pr[0];
        else if (lane == 5) x1 = ts[0];

        const float4* h04 = (const float4*)h0;
        const float4  hA = h04[lane], hB = h04[64 + lane];
        const float4* wh4 = (const float4*)(Wh + (size_t)row * HDIM);
        const float4 a0 = wh4[lane], a1 = wh4[64 + lane];
        float acc = a0.x*hA.x + a0.y*hA.y + a0.z*hA.z + a0.w*hA.w
                  + a1.x*hB.x + a1.y*hB.y + a1.z*hB.z + a1.w*hB.w;
        const float* wxr = Wx + (size_t)row * 70;
        acc += wxr[lane] * x0;
        if (lane < 6) acc += wxr[64 + lane] * x1;
        acc = wave_sum(acc);
        if (lane == 0) ws[PREACT_OFF + row] = acc + b[row];
    }

    // ---- sims sweep: 4-row groups, 8 dwordx4 loads in flight, ILP'd reduce --
    const float4* c4 = (const float4*)cue;
    const float4 cA = c4[lane], cB = c4[64 + lane];
    float minss = INFINITY;

    const int NG = NROWS / 4;                    // 25000 groups (NROWS % 4 == 0)
    for (int g = gw; g < NG; g += nw) {
        const int n = g * 4;                     // rows n..n+3
        const float* r = K + (size_t)n * HDIM;
        const float4* p0 = (const float4*)(r);
        const float4* p1 = (const float4*)(r + HDIM);
        const float4* p2 = (const float4*)(r + 2 * HDIM);
        const float4* p3 = (const float4*)(r + 3 * HDIM);
        const float4 a0 = p0[lane], b0 = p0[64 + lane];
        const float4 a1 = p1[lane], b1 = p1[64 + lane];
        const float4 a2 = p2[lane], b2 = p2[64 + lane];
        const float4 a3 = p3[lane], b3 = p3[64 + lane];
        float s0 = d2sum(a0, cA) + d2sum(b0, cB);
        float s1 = d2sum(a1, cA) + d2sum(b1, cB);
        float s2 = d2sum(a2, cA) + d2sum(b2, cB);
        float s3 = d2sum(a3, cA) + d2sum(b3, cB);
        #pragma unroll
        for (int off = 32; off; off >>= 1) {     // 4 independent chains, ILP
            s0 += __shfl_xor(s0, off);
            s1 += __shfl_xor(s1, off);
            s2 += __shfl_xor(s2, off);
            s3 += __shfl_xor(s3, off);
        }
        if (lane == 0) {                         // n%4==0 -> 16B aligned
            *(float4*)&ws[SIMS_OFF + n] = make_float4(-s0, -s1, -s2, -s3);
        }
        minss = fminf(fminf(minss, s0), fminf(fminf(s1, s2), s3));
    }

    minss = wave_min(minss);
    __shared__ float smin[4];
    if (lane == 0) smin[wib] = minss;
    __syncthreads();
    if (threadIdx.x == 0)
        ws[BMIN_OFF + blockIdx.x] =
            fminf(fminf(smin[0], smin[1]), fminf(smin[2], smin[3]));
}

// ====== kernel B: global max + gather + partials + ticketed final ============
__global__ __launch_bounds__(256)
void kB(const float* __restrict__ V, const float* __restrict__ c0,
        const float* __restrict__ aw, const float* __restrict__ ab,
        const float* __restrict__ cw, const float* __restrict__ cb,
        float* __restrict__ ws, float* __restrict__ out) {
    const int lane = threadIdx.x & 63;
    const int wib  = threadIdx.x >> 6;
    const int t    = threadIdx.x;

    // ---- every block computes the identical global max (deterministic) ----
    float mn = INFINITY;
    #pragma unroll
    for (int i = 0; i < NBLK_A / 256; i++)
        mn = fminf(mn, ws[BMIN_OFF + i * 256 + t]);
    mn = wave_min(mn);
    __shared__ float sred[4];
    if (lane == 0) sred[wib] = mn;
    __syncthreads();
    const float smax = -fminf(fminf(sred[0], sred[1]), fminf(sred[2], sred[3]));

    // ---- gather surviving V rows ----
    const int gwid = blockIdx.x * 4 + wib;        // 256 gather waves
    float4 accA = {0.f,0.f,0.f,0.f}, accB = {0.f,0.f,0.f,0.f};
    float dsum = 0.f;

    const int nchunks = (NROWS + 63) / 64;
    for (int c = gwid; c < nchunks; c += NBLK_B * 4) {
        const int n = c * 64 + lane;
        const bool valid = (n < NROWS);
        const float s = valid ? ws[SIMS_OFF + n] : -INFINITY;
        const float e = expf(s - smax);          // underflows to 0 for far rows
        dsum += e;                                // exact denominator
        unsigned long long mask = __ballot(valid && (s - smax >= -30.0f));
        while (mask) {
            const int bpos = __ffsll(mask) - 1;
            mask &= mask - 1;
            const int nb = c * 64 + bpos;
            const float eb = __shfl(e, bpos);
            const float4* v4 = (const float4*)(V + (size_t)nb * HDIM);
            const float4 vA = v4[lane], vB = v4[64 + lane];
            accA.x += eb * vA.x; accA.y += eb * vA.y;
            accA.z += eb * vA.z; accA.w += eb * vA.w;
            accB.x += eb * vB.x; accB.y += eb * vB.y;
            accB.z += eb * vB.z; accB.w += eb * vB.w;
        }
    }
    dsum = wave_sum(dsum);

    __shared__ float lm[4][HDIM];
    __shared__ float ld[4];
    {
        float* rowp = lm[wib];
        rowp[lane*4 + 0]       = accA.x; rowp[lane*4 + 1]       = accA.y;
        rowp[lane*4 + 2]       = accA.z; rowp[lane*4 + 3]       = accA.w;
        rowp[256 + lane*4 + 0] = accB.x; rowp[256 + lane*4 + 1] = accB.y;
        rowp[256 + lane*4 + 2] = accB.z; rowp[256 + lane*4 + 3] = accB.w;
        if (lane == 0) ld[wib] = dsum;
    }
    __syncthreads();

    ws[PM_OFF + blockIdx.x * HDIM + t] =
        lm[0][t] + lm[1][t] + lm[2][t] + lm[3][t];
    ws[PM_OFF + blockIdx.x * HDIM + 256 + t] =
        lm[0][256+t] + lm[1][256+t] + lm[2][256+t] + lm[3][256+t];
    if (t == 0)
        ws[PD_OFF + blockIdx.x] = ld[0] + ld[1] + ld[2] + ld[3];

    // ---- ticket: last block to finish does the final reduce + cell + heads --
    __threadfence();                              // release partials (device scope)
    __shared__ int sOld;
    if (t == 0) sOld = atomicAdd((int*)ws + CNT_OFF, 1);
    __syncthreads();
    if (sOld != NBLK_B - 1) return;
    __threadfence();                              // acquire others' partials

    __shared__ float hl[HDIM];
    __shared__ float sden;
    __shared__ float logits[4];

    if (wib == 0) {
        float d = ws[PD_OFF + lane];              // 64 partials, one per lane
        d = wave_sum(d);
        if (lane == 0) sden = d;
    }
    float m0 = 0.f, m1 = 0.f;
    #pragma unroll 8
    for (int b2 = 0; b2 < NBLK_B; b2++) {
        m0 += ws[PM_OFF + b2 * HDIM + t];
        m1 += ws[PM_OFF + b2 * HDIM + 256 + t];
    }
    __syncthreads();
    const float inv_den = 1.f / sden;
    m0 *= inv_den; m1 *= inv_den;

    #pragma unroll
    for (int half = 0; half < 2; half++) {
        const int tt = t + half * 256;
        const float mm = half ? m1 : m0;
        const float pf = ws[PREACT_OFF + tt];
        const float pi = ws[PREACT_OFF + HDIM + tt];
        const float po = ws[PREACT_OFF + 2*HDIM + tt];
        const float prg= ws[PREACT_OFF + 3*HDIM + tt];
        const float pc = ws[PREACT_OFF + 4*HDIM + tt];
        const float f_t = 1.f / (1.f + expf(-pf));
        const float i_t = 1.f / (1.f + expf(-pi));
        const float o_t = 1.f / (1.f + expf(-po));
        const float r_t = 1.f / (1.f + expf(-prg));
        const float chat = tanhf(pc);
        const float ct = f_t * c0[tt] + i_t * chat + r_t * mm;
        const float ht = o_t * tanhf(ct);
        out[517 + tt] = ct;
        out[5 + tt]   = ht;
        hl[tt] = ht;
    }
    __syncthreads();

    if (wib < 4) {       // actor logits, one wave per row
        float acc = 0.f;
        #pragma unroll
        for (int j = 0; j < HDIM; j += 64)
            acc += aw[wib * HDIM + j + lane] * hl[j + lane];
        acc = wave_sum(acc);
        if (lane == 0) logits[wib] = acc + ab[wib];
    }
    if (wib == 0) {      // critic
        float acc = 0.f;
        #pragma unroll
        for (int j = 0; j < HDIM; j += 64)
            acc += cw[j + lane] * hl[j + lane];
        acc = wave_sum(acc);
        if (lane == 0) out[4] = acc + cb[0];
    }
    __syncthreads();

    if (t == 0) {
        const float mx = fmaxf(fmaxf(logits[0], logits[1]),
                               fmaxf(logits[2], logits[3]));
        const float e0 = expf(logits[0] - mx), e1 = expf(logits[1] - mx);
        const float e2 = expf(logits[2] - mx), e3 = expf(logits[3] - mx);
        const float inv = 1.f / (e0 + e1 + e2 + e3);
        out[0] = e0 * inv; out[1] = e1 * inv;
        out[2] = e2 * inv; out[3] = e3 * inv;
    }
}

extern "C" void kernel_launch(void* const* d_in, const int* in_sizes, int n_in,
                              void* d_out, int out_size, void* d_ws, size_t ws_size,
                              hipStream_t stream) {
    const float* state  = (const float*)d_in[0];
    const float* pa     = (const float*)d_in[1];
    const float* pr     = (const float*)d_in[2];
    const float* ts     = (const float*)d_in[3];
    const float* cue    = (const float*)d_in[4];
    const float* keys   = (const float*)d_in[5];
    const float* vals   = (const float*)d_in[6];
    const float* Wx     = (const float*)d_in[7];
    const float* Wh     = (const float*)d_in[8];
    const float* b      = (const float*)d_in[9];
    const float* aw     = (const float*)d_in[10];
    const float* ab     = (const float*)d_in[11];
    const float* cw     = (const float*)d_in[12];
    const float* cb     = (const float*)d_in[13];
    const float* h0     = (const float*)d_in[14];
    const float* c0     = (const float*)d_in[15];
    float* ws  = (float*)d_ws;
    float* out = (float*)d_out;

    kA<<<NBLK_A, 256, 0, stream>>>(state, pa, pr, ts, cue, keys, Wx, Wh, b, h0, ws);
    kB<<<NBLK_B, 256, 0, stream>>>(vals, c0, aw, ab, cw, cb, ws, out);
}